// Round 1
// baseline (3419.303 us; speedup 1.0000x reference)
//
#include <hip/hip_runtime.h>
#include <cstdint>
#include <cmath>

// Workspace layout (bytes):
//   h      : 0            .. 67108864   (8*512*64*64 f32)
//   boxes  : 67108864     .. 71827456   (8*36864*4 f32)
//   scores : 71827456     .. 73007104   (8*36864 f32)
//   sel    : 73007104     .. 73199104   (8*6000 u32)
// requires ws_size >= 73199104 (~70 MB)

// ---------------- Stage A: 3x3 conv + bias + relu (fp32) ----------------
// block: 256 thr = (yy:2) x (coq:16 -> 4 co each) x (xq:8 -> 8 x each)
// tile per block: 64 co x 64 x x 2 y ; K staged in ci-chunks of 8.
__global__ __launch_bounds__(256) void k_conv3x3(
        const float* __restrict__ x, const float* __restrict__ w,
        const float* __restrict__ bias, float* __restrict__ hout) {
    __shared__ __align__(16) float xs[8][4][68];   // [ci][row][x+1], rows y0-1..y0+2
    __shared__ __align__(16) float wl[8][9][64];   // [ci][ky*3+kx][co]
    const int ypair = blockIdx.x;
    const int co0 = blockIdx.y * 64;
    const int b = blockIdx.z;
    const int t = threadIdx.x;
    const int xq = t & 7;
    const int coq = (t >> 3) & 15;
    const int yy = t >> 7;
    const int y0 = ypair * 2;

    float acc[4][8];
#pragma unroll
    for (int c = 0; c < 4; ++c)
#pragma unroll
        for (int i = 0; i < 8; ++i) acc[c][i] = 0.f;

    const int co_s = t >> 2, q_s = t & 3;

    for (int ci0 = 0; ci0 < 512; ci0 += 8) {
        __syncthreads();
        // stage x: 8 ci * 4 rows * 66 cols (with zero halo)
        for (int idx = t; idx < 2112; idx += 256) {
            int ci = idx / 264;
            int rem = idx - ci * 264;
            int ry = rem / 66;
            int xx = rem - ry * 66 - 1;           // -1..64
            int gy = y0 - 1 + ry;
            float v = 0.f;
            if (gy >= 0 && gy < 64 && xx >= 0 && xx < 64)
                v = x[(((size_t)b * 512 + ci0 + ci) * 64 + gy) * 64 + xx];
            xs[ci][ry][xx + 1] = v;
        }
        // stage w: 64 co * 8 ci * 9
        {
            const float* wp = w + ((size_t)(co0 + co_s) * 512 + ci0) * 9 + q_s * 18;
#pragma unroll
            for (int j = 0; j < 18; ++j) {
                int f = q_s * 18 + j;
                int ci = f / 9, kk = f - ci * 9;
                wl[ci][kk][co_s] = wp[j];
            }
        }
        __syncthreads();
#pragma unroll
        for (int ci = 0; ci < 8; ++ci) {
#pragma unroll
            for (int ky = 0; ky < 3; ++ky) {
                const float* xr = &xs[ci][yy + ky][xq * 8];
                float4 v0 = *reinterpret_cast<const float4*>(xr);
                float4 v1 = *reinterpret_cast<const float4*>(xr + 4);
                float xv[10];
                xv[0] = v0.x; xv[1] = v0.y; xv[2] = v0.z; xv[3] = v0.w;
                xv[4] = v1.x; xv[5] = v1.y; xv[6] = v1.z; xv[7] = v1.w;
                xv[8] = xr[8]; xv[9] = xr[9];
#pragma unroll
                for (int kx = 0; kx < 3; ++kx) {
                    const float4 wv = *reinterpret_cast<const float4*>(&wl[ci][ky * 3 + kx][coq * 4]);
#pragma unroll
                    for (int i = 0; i < 8; ++i) {
                        float xvv = xv[i + kx];
                        acc[0][i] += wv.x * xvv;
                        acc[1][i] += wv.y * xvv;
                        acc[2][i] += wv.z * xvv;
                        acc[3][i] += wv.w * xvv;
                    }
                }
            }
        }
    }
    const int y = y0 + yy;
#pragma unroll
    for (int c = 0; c < 4; ++c) {
        const int co = co0 + coq * 4 + c;
        const float bv = bias[co];
        float* op = hout + (((size_t)b * 512 + co) * 64 + y) * 64 + xq * 8;
#pragma unroll
        for (int i = 0; i < 8; ++i) {
            float v = acc[c][i] + bv;
            op[i] = v > 0.f ? v : 0.f;
        }
    }
}

// ---------------- Stage B: 1x1 heads + sigmoid + decode ----------------
__global__ __launch_bounds__(256) void k_head(
        const float* __restrict__ h,
        const float* __restrict__ cls_w, const float* __restrict__ cls_b,
        const float* __restrict__ loc_w, const float* __restrict__ loc_b,
        const int* __restrict__ img_h_p, const int* __restrict__ img_w_p,
        float* __restrict__ out_cls, float* __restrict__ out_loc,
        float* __restrict__ boxes, float* __restrict__ scores) {
    const int tg = blockIdx.x * 256 + threadIdx.x;   // 0..32767
    const int b = tg >> 12;
    const int pos = tg & 4095;
    const int y = pos >> 6, xc = pos & 63;
    float accC[18], accL[36];
#pragma unroll
    for (int o = 0; o < 18; ++o) accC[o] = 0.f;
#pragma unroll
    for (int o = 0; o < 36; ++o) accL[o] = 0.f;
    const float* hp = h + (size_t)b * 2097152 + pos;
#pragma unroll 4
    for (int ci = 0; ci < 512; ++ci) {
        const float hv = hp[(size_t)ci * 4096];
#pragma unroll
        for (int o = 0; o < 18; ++o) accC[o] += cls_w[o * 512 + ci] * hv;
#pragma unroll
        for (int o = 0; o < 36; ++o) accL[o] += loc_w[o * 512 + ci] * hv;
    }
    const float fh = (float)(*img_h_p);
    const float fw = (float)(*img_w_p);
    {
        const size_t obase = (size_t)b * 73728 + (size_t)pos * 18;
#pragma unroll
        for (int o = 0; o < 18; ++o) {
            accC[o] += cls_b[o];
            out_cls[obase + o] = 1.f / (1.f + expf(-accC[o]));
        }
    }
    {
        const size_t lbase = (size_t)b * 147456 + (size_t)pos * 36;
#pragma unroll
        for (int o = 0; o < 36; ++o) {
            accL[o] += loc_b[o];
            out_loc[lbase + o] = accL[o];
        }
    }
    const float sy = (float)(y * 16), sx = (float)(xc * 16);
    const double RR[3] = {0.5, 1.0, 2.0};
    const double SS[3] = {8.0, 16.0, 32.0};
#pragma unroll
    for (int a = 0; a < 9; ++a) {
        const double r = RR[a / 3], s = SS[a % 3];
        const double hd = 16.0 * s * sqrt(r);
        const double wd = 16.0 * s * sqrt(1.0 / r);
        const float ab0 = (float)(-hd / 2.0), ab1 = (float)(-wd / 2.0);
        const float ab2 = (float)(hd / 2.0), ab3 = (float)(wd / 2.0);
        const float a0 = ab0 + sy, a1 = ab1 + sx, a2 = ab2 + sy, a3 = ab3 + sx;
        float hh = a2 - a0, ww = a3 - a1;
        float cy = a0 + 0.5f * hh, cx = a1 + 0.5f * ww;
        const float dy = accL[a * 4 + 0], dx = accL[a * 4 + 1];
        const float dh = accL[a * 4 + 2], dw = accL[a * 4 + 3];
        cy = cy + dy * hh;
        cx = cx + dx * ww;
        hh = hh * expf(dh);
        ww = ww * expf(dw);
        float y1 = cy - 0.5f * hh, x1 = cx - 0.5f * ww;
        float y2 = cy + 0.5f * hh, x2 = cx + 0.5f * ww;
        y1 = fminf(fmaxf(y1, 0.f), fh); x1 = fminf(fmaxf(x1, 0.f), fw);
        y2 = fminf(fmaxf(y2, 0.f), fh); x2 = fminf(fmaxf(x2, 0.f), fw);
        const bool valid = ((y2 - y1) >= 16.f) && ((x2 - x1) >= 16.f);
        const float sc = 1.f / (1.f + expf(-accC[a * 2 + 1]));
        const int n = pos * 9 + a;
        float* bp = boxes + ((size_t)b * 36864 + n) * 4;
        bp[0] = y1; bp[1] = x1; bp[2] = y2; bp[3] = x2;
        scores[(size_t)b * 36864 + n] = valid ? sc : -INFINITY;
    }
}

// ---------------- Stage C: exact top-6000 select (radix) ----------------
__device__ __forceinline__ unsigned fmap(float f) {
    unsigned bits = __float_as_uint(f);
    return ((int)bits < 0) ? ~bits : (bits | 0x80000000u);
}

__global__ __launch_bounds__(1024) void k_select(
        const float* __restrict__ scores, unsigned* __restrict__ sel) {
    __shared__ unsigned hist[256];
    __shared__ unsigned tieL[1024];
    __shared__ unsigned sh_pref, sh_k, sh_cg, sh_ct;
    const int b = blockIdx.x;
    const int t = threadIdx.x;
    const float* sp = scores + (size_t)b * 36864;
    unsigned pref = 0;
    unsigned k = 6000;
    for (int p = 3; p >= 0; --p) {
        if (t < 256) hist[t] = 0;
        __syncthreads();
        for (int i = t; i < 36864; i += 1024) {
            unsigned u = fmap(sp[i]);
            bool match = (p == 3) || ((u >> ((p + 1) * 8)) == (pref >> ((p + 1) * 8)));
            if (match) atomicAdd(&hist[(u >> (p * 8)) & 255], 1u);
        }
        __syncthreads();
        if (t == 0) {
            unsigned c = 0;
            int bsel = 0;
            for (int bin = 255; bin >= 0; --bin) {
                unsigned c2 = c + hist[bin];
                if (c2 >= k) { bsel = bin; k = k - c; break; }
                c = c2;
            }
            pref |= ((unsigned)bsel) << (p * 8);
            sh_pref = pref; sh_k = k;
        }
        __syncthreads();
        pref = sh_pref; k = sh_k;
        __syncthreads();
    }
    if (t == 0) { sh_cg = 0; sh_ct = 0; }
    __syncthreads();
    const unsigned uthr = pref;
    for (int i = t; i < 36864; i += 1024) {
        unsigned u = fmap(sp[i]);
        if (u > uthr) {
            unsigned posn = atomicAdd(&sh_cg, 1u);
            sel[(size_t)b * 6000 + posn] = (unsigned)i;
        } else if (u == uthr) {
            unsigned tp = atomicAdd(&sh_ct, 1u);
            if (tp < 1024) tieL[tp] = (unsigned)i;
        }
    }
    __syncthreads();
    const unsigned G = sh_cg;
    const unsigned T = sh_ct;
    const unsigned need = k;   // 6000 - G
    const unsigned Tc = T < 1024u ? T : 1024u;
    if ((unsigned)t >= Tc) tieL[t] = 0xFFFFFFFFu;
    __syncthreads();
    if (need > 0) {
        if (T > 1) {
            for (int kk = 2; kk <= 1024; kk <<= 1) {
                for (int j = kk >> 1; j > 0; j >>= 1) {
                    int ixj = t ^ j;
                    if (ixj > t) {
                        unsigned va = tieL[t], vb = tieL[ixj];
                        bool up = ((t & kk) == 0);
                        if (up ? (va > vb) : (va < vb)) { tieL[t] = vb; tieL[ixj] = va; }
                    }
                    __syncthreads();
                }
            }
        }
        if ((unsigned)t < need) sel[(size_t)b * 6000 + G + t] = tieL[t];
    }
}

// ---------------- Stage D: sequential 300-pick NMS ----------------
__global__ __launch_bounds__(1024) void k_nms(
        const float* __restrict__ boxes, const float* __restrict__ scores,
        const unsigned* __restrict__ sel,
        float* __restrict__ rois, float* __restrict__ roi_idx) {
    __shared__ unsigned long long warr[16];
    __shared__ unsigned long long winK;
    const int b = blockIdx.x;
    const int t = threadIdx.x;
    const unsigned UNEG = 0x007FFFFFu;  // fmap(-inf)
    float bx[6][4];
    unsigned long long key[6];
#pragma unroll
    for (int j = 0; j < 6; ++j) {
        int s = t + j * 1024;
        if (s < 6000) {
            unsigned idx = sel[(size_t)b * 6000 + s];
            const float* bp = boxes + ((size_t)b * 36864 + idx) * 4;
            bx[j][0] = bp[0]; bx[j][1] = bp[1]; bx[j][2] = bp[2]; bx[j][3] = bp[3];
            unsigned u = fmap(scores[(size_t)b * 36864 + idx]);
            key[j] = ((unsigned long long)u << 32) | (unsigned)(~idx);
        } else {
            key[j] = 0ull;
            bx[j][0] = bx[j][1] = bx[j][2] = bx[j][3] = 0.f;
        }
    }
    const int lane = t & 63;
    const int wid = t >> 6;
    float* orow = rois + (size_t)b * 300 * 4;
    for (int k = 0; k < 300; ++k) {
        unsigned long long m = key[0];
#pragma unroll
        for (int j = 1; j < 6; ++j) m = key[j] > m ? key[j] : m;
#pragma unroll
        for (int d = 32; d > 0; d >>= 1) {
            unsigned long long o = __shfl_xor(m, d, 64);
            if (o > m) m = o;
        }
        if (lane == 0) warr[wid] = m;
        __syncthreads();
        if (t == 0) {
            unsigned long long wv = warr[0];
#pragma unroll
            for (int i = 1; i < 16; ++i) if (warr[i] > wv) wv = warr[i];
            winK = wv;
        }
        __syncthreads();
        const unsigned long long wk = winK;
        const unsigned uhi = (unsigned)(wk >> 32);
        if (uhi > UNEG) {
            const unsigned widx = ~(unsigned)wk;
            const float* bp = boxes + ((size_t)b * 36864 + widx) * 4;
            const float py1 = bp[0], px1 = bp[1], py2 = bp[2], px2 = bp[3];
            const float parea = (py2 - py1) * (px2 - px1);
            if (t == 0) {
                orow[k * 4 + 0] = py1; orow[k * 4 + 1] = px1;
                orow[k * 4 + 2] = py2; orow[k * 4 + 3] = px2;
                roi_idx[b * 300 + k] = (float)b;
            }
#pragma unroll
            for (int j = 0; j < 6; ++j) {
                if ((unsigned)(key[j] >> 32) > UNEG) {
                    float yy1 = fmaxf(bx[j][0], py1);
                    float xx1 = fmaxf(bx[j][1], px1);
                    float yy2 = fminf(bx[j][2], py2);
                    float xx2 = fminf(bx[j][3], px2);
                    float inter = fmaxf(yy2 - yy1, 0.f) * fmaxf(xx2 - xx1, 0.f);
                    float area = (bx[j][2] - bx[j][0]) * (bx[j][3] - bx[j][1]);
                    float iou = inter / (area + parea - inter + 1e-9f);
                    if (iou > 0.7f)
                        key[j] = ((unsigned long long)UNEG << 32) | (key[j] & 0xFFFFFFFFull);
                }
            }
        } else {
            if (t == 0) {
                orow[k * 4 + 0] = 0.f; orow[k * 4 + 1] = 0.f;
                orow[k * 4 + 2] = 0.f; orow[k * 4 + 3] = 0.f;
                roi_idx[b * 300 + k] = (float)b;
            }
        }
        __syncthreads();
    }
}

extern "C" void kernel_launch(void* const* d_in, const int* in_sizes, int n_in,
                              void* d_out, int out_size, void* d_ws, size_t ws_size,
                              hipStream_t stream) {
    (void)in_sizes; (void)n_in; (void)out_size; (void)ws_size;
    const float* x      = (const float*)d_in[0];
    const float* conv_w = (const float*)d_in[1];
    const float* conv_b = (const float*)d_in[2];
    const float* loc_w  = (const float*)d_in[3];
    const float* loc_b  = (const float*)d_in[4];
    const float* cls_w  = (const float*)d_in[5];
    const float* cls_b  = (const float*)d_in[6];
    const int* img_h    = (const int*)d_in[7];
    const int* img_w    = (const int*)d_in[8];

    char* ws = (char*)d_ws;
    float*    h      = (float*)(ws + 0);
    float*    boxes  = (float*)(ws + 67108864);
    float*    scores = (float*)(ws + 71827456);
    unsigned* sel    = (unsigned*)(ws + 73007104);

    float* out      = (float*)d_out;
    float* out_cls  = out;             // 589824
    float* out_loc  = out + 589824;    // 1179648
    float* rois     = out + 1769472;   // 9600
    float* ridx     = out + 1779072;   // 2400

    k_conv3x3<<<dim3(32, 8, 8), 256, 0, stream>>>(x, conv_w, conv_b, h);
    k_head<<<dim3(128), 256, 0, stream>>>(h, cls_w, cls_b, loc_w, loc_b,
                                          img_h, img_w, out_cls, out_loc, boxes, scores);
    k_select<<<dim3(8), 1024, 0, stream>>>(scores, sel);
    k_nms<<<dim3(8), 1024, 0, stream>>>(boxes, scores, sel, rois, ridx);
}